// Round 4
// baseline (294.743 us; speedup 1.0000x reference)
//
#include <hip/hip_runtime.h>
#include <math.h>

#define N_PATHS 23
#define HIDDEN  32
#define N_NODES 4096
#define N_EDGES 8192
#define FEAT    512
#define EB      8     // edges per block

// ---- path metadata (PATHS enumeration order: l1 outer, l2, l3) ----
__device__ const int P_L1[N_PATHS] = {0,0,0,0, 1,1,1,1,1,1, 2,2,2,2,2,2,2, 3,3,3,3,3,3};
__device__ const int P_L2[N_PATHS] = {0,1,2,3, 0,1,1,2,2,3, 0,1,1,2,2,3,3, 0,1,2,2,3,3};
__device__ const int P_L3[N_PATHS] = {0,1,2,3, 1,0,2,1,3,2, 2,1,3,0,2,1,3, 3,2,1,3,0,2};
__device__ const int C_OFF[N_PATHS] = {0,1,10,35,84,93,102,147,192,297,402,427,472,577,602,727,832,1077,1126,1231,1336,1581,1630};
__device__ const int CNT_L3[4] = {4,6,7,6};

// ---- 16-point Gauss-Legendre nodes/weights ----
__device__ const double GLX[16] = {
    -0.98940093499164993, -0.94457502307323258, -0.86563120238783174, -0.75540440835500303,
    -0.61787624440264375, -0.45801677765722739, -0.28160355077925891, -0.09501250983763744,
     0.09501250983763744,  0.28160355077925891,  0.45801677765722739,  0.61787624440264375,
     0.75540440835500303,  0.86563120238783174,  0.94457502307323258,  0.98940093499164993};
__device__ const double GLW[16] = {
     0.02715245941175409,  0.06225352393864789,  0.09515851168249278,  0.12462897125553387,
     0.14959598881657673,  0.16915651939500254,  0.18260341504492359,  0.18945061045506850,
     0.18945061045506850,  0.18260341504492359,  0.16915651939500254,  0.14959598881657673,
     0.12462897125553387,  0.09515851168249278,  0.06225352393864789,  0.02715245941175409};

// cos/sin(k*pi/16), k=0..31 — exact literals, no device transcendentals
__device__ const double COSP[32] = {
  1.0,                    0.980785280403230449,  0.923879532511286756,  0.831469612302545237,
  0.707106781186547524,   0.555570233019602225,  0.382683432365089772,  0.195090322016128268,
  0.0,                   -0.195090322016128268, -0.382683432365089772, -0.555570233019602225,
 -0.707106781186547524,  -0.831469612302545237, -0.923879532511286756, -0.980785280403230449,
 -1.0,                   -0.980785280403230449, -0.923879532511286756, -0.831469612302545237,
 -0.707106781186547524,  -0.555570233019602225, -0.382683432365089772, -0.195090322016128268,
  0.0,                    0.195090322016128268,  0.382683432365089772,  0.555570233019602225,
  0.707106781186547524,   0.831469612302545237,  0.923879532511286756,  0.980785280403230449};
__device__ const double SINP[32] = {
  0.0,                    0.195090322016128268,  0.382683432365089772,  0.555570233019602225,
  0.707106781186547524,   0.831469612302545237,  0.923879532511286756,  0.980785280403230449,
  1.0,                    0.980785280403230449,  0.923879532511286756,  0.831469612302545237,
  0.707106781186547524,   0.555570233019602225,  0.382683432365089772,  0.195090322016128268,
  0.0,                   -0.195090322016128268, -0.382683432365089772, -0.555570233019602225,
 -0.707106781186547524,  -0.831469612302545237, -0.923879532511286756, -0.980785280403230449,
 -1.0,                   -0.980785280403230449, -0.923879532511286756, -0.831469612302545237,
 -0.707106781186547524,  -0.555570233019602225, -0.382683432365089772, -0.195090322016128268};

__device__ inline void sh_f64(double x, double y, double z, double* Y) {
    const double s3 = 1.7320508075688772935, s5 = 2.2360679774997896964,
                 s7 = 2.6457513110645905905, s15 = 3.8729833462074168852;
    const double c58 = 0.79056941504209483300, c38 = 0.61237243569579452455;
    Y[0] = 1.0;
    Y[1] = s3*x;  Y[2] = s3*y;  Y[3] = s3*z;
    Y[4] = s5*s3*x*z;
    Y[5] = s5*s3*x*y;
    Y[6] = s5*(y*y - 0.5*(x*x + z*z));
    Y[7] = s5*s3*y*z;
    Y[8] = s5*(s3/2.0)*(z*z - x*x);
    Y[9] = s7*c58*x*(3.0*z*z - x*x);
    Y[10]= s7*s15*x*y*z;
    Y[11]= s7*c38*x*(5.0*y*y - 1.0);
    Y[12]= s7*0.5*y*(5.0*y*y - 3.0);
    Y[13]= s7*c38*z*(5.0*y*y - 1.0);
    Y[14]= s7*(s15/2.0)*y*(z*z - x*x);
    Y[15]= s7*c58*z*(z*z - 3.0*x*x);
}

__device__ inline void sh_f32(float x, float y, float z, float* Y) {
    const float s3 = 1.73205080757f, s5 = 2.23606797750f, s7 = 2.64575131106f, s15 = 3.87298334621f;
    const float c58 = 0.79056941504f, c38 = 0.61237243570f;
    Y[0] = 1.0f;
    Y[1] = s3*x;  Y[2] = s3*y;  Y[3] = s3*z;
    Y[4] = s15*x*z;
    Y[5] = s15*x*y;
    Y[6] = s5*(y*y - 0.5f*(x*x + z*z));
    Y[7] = s15*y*z;
    Y[8] = s5*(s3*0.5f)*(z*z - x*x);
    Y[9] = s7*c58*x*(3.0f*z*z - x*x);
    Y[10]= s7*s15*x*y*z;
    Y[11]= s7*c38*x*(5.0f*y*y - 1.0f);
    Y[12]= s7*0.5f*y*(5.0f*y*y - 3.0f);
    Y[13]= s7*c38*z*(5.0f*y*y - 1.0f);
    Y[14]= s7*(s15*0.5f)*y*(z*z - x*x);
    Y[15]= s7*c58*z*(z*z - 3.0f*x*x);
}

// ---- setup: build (PATH_W * W3J / ||W3J||) tables, fp32 throughout ----
__global__ __launch_bounds__(256) void w3j_setup_kernel(float* __restrict__ g_w3j) {
    __shared__ float s_Yq[512][16];
    __shared__ float s_wq[512];
    __shared__ float red[256];
    __shared__ float s_scale;

    const int p = blockIdx.x;
    const int t = threadIdx.x;
    const int l1 = P_L1[p], l2 = P_L2[p], l3 = P_L3[p];
    const int d1 = 2*l1+1, d2 = 2*l2+1, d3 = 2*l3+1;
    const int csize = d1*d2*d3;

    const double step = 2.0*3.14159265358979323846/32.0;

#pragma unroll
    for (int r = 0; r < 2; ++r) {
        const int q = t + 256*r;
        const int iu = q >> 5, ip = q & 31;
        const double u = GLX[iu];
        const double st = sqrt(fmax(1.0 - u*u, 0.0));
        double Y[16];
        sh_f64(st*COSP[ip], st*SINP[ip], u, Y);
#pragma unroll
        for (int i = 0; i < 16; ++i) s_Yq[q][i] = (float)Y[i];
        s_wq[q] = (float)(GLW[iu] * step);
    }
    __syncthreads();

    const int idx0 = t, idx1 = t + 256;
    const bool v0 = idx0 < csize, v1 = idx1 < csize;
    int a0i=0,b0i=0,c0i=0, a1i=0,b1i=0,c1i=0;
    if (v0) { int i = idx0/(d2*d3); int r = idx0 - i*(d2*d3); int j = r/d3; int k = r - j*d3;
              a0i = l1*l1+i; b0i = l2*l2+j; c0i = l3*l3+k; }
    if (v1) { int i = idx1/(d2*d3); int r = idx1 - i*(d2*d3); int j = r/d3; int k = r - j*d3;
              a1i = l1*l1+i; b1i = l2*l2+j; c1i = l3*l3+k; }

    // fp32 accumulation, 2 independent partials each for ILP
    float a0A=0.f, a0B=0.f, a1A=0.f, a1B=0.f;
#pragma unroll 4
    for (int q = 0; q < 512; q += 2) {
        const float w0 = s_wq[q], w1 = s_wq[q+1];
        if (v0) {
            a0A = fmaf(w0 * s_Yq[q][a0i]   * s_Yq[q][b0i],   s_Yq[q][c0i],   a0A);
            a0B = fmaf(w1 * s_Yq[q+1][a0i] * s_Yq[q+1][b0i], s_Yq[q+1][c0i], a0B);
        }
        if (v1) {
            a1A = fmaf(w0 * s_Yq[q][a1i]   * s_Yq[q][b1i],   s_Yq[q][c1i],   a1A);
            a1B = fmaf(w1 * s_Yq[q+1][a1i] * s_Yq[q+1][b1i], s_Yq[q+1][c1i], a1B);
        }
    }
    const float a0 = a0A + a0B, a1 = a1A + a1B;

    red[t] = a0*a0 + a1*a1;
    __syncthreads();
    for (int s = 128; s > 0; s >>= 1) {
        if (t < s) red[t] += red[t+s];
        __syncthreads();
    }
    if (t == 0) {
        const float nrm = sqrtf(red[0]);
        const float pw  = sqrtf((float)(2*l3+1) / ((float)CNT_L3[l3] * (float)HIDDEN));
        s_scale = pw / nrm;
    }
    __syncthreads();
    if (v0) g_w3j[C_OFF[p] + idx0] = a0 * s_scale;
    if (v1) g_w3j[C_OFF[p] + idx1] = a1 * s_scale;
}

// ---- per-path GEMM: thread=(e,w); weights one b64/u; msg stays in registers ----
template<int D3>
__device__ inline void gemm_path(int te, int tw, const float* __restrict__ s_tmp,
                                 const float2* __restrict__ s_wwb,
                                 float len, float* __restrict__ msg) {
    const float* tp = s_tmp + te*256;   // [u][8]
    float accw[D3], accb[D3];
#pragma unroll
    for (int k = 0; k < D3; ++k) { accw[k] = 0.f; accb[k] = 0.f; }
#pragma unroll
    for (int u = 0; u < 32; ++u) {
        const float2 wv = s_wwb[u*32 + tw];  // (wb, ww): banks 2w -> 2-way free
        const float* tu = tp + u*8;          // half-wave broadcast, b128-able
#pragma unroll
        for (int k = 0; k < D3; ++k) {
            const float tv = tu[k];
            accb[k] = fmaf(tv, wv.x, accb[k]);
            accw[k] = fmaf(tv, wv.y, accw[k]);
        }
    }
#pragma unroll
    for (int k = 0; k < D3; ++k) msg[k] += fmaf(len, accw[k], accb[k]);
}

// ---- main: 8 edges per block, message accumulators in registers ----
__global__ __launch_bounds__(256) void edge_kernel(
    const float* __restrict__ nf,   // (N_NODES, FEAT)
    const int*   __restrict__ eidx, // (2, N_EDGES)
    const float* __restrict__ ev,   // (N_EDGES, 3)
    const float* __restrict__ ww,   // (23552,)
    const float* __restrict__ wb,   // (23552,)
    const float* __restrict__ w3j,  // (1875,)
    float*       __restrict__ out)  // (N_NODES, FEAT) pre-zeroed
{
    __shared__ float  s_x[EB*FEAT];      // 16 KB gathered features
    __shared__ float  s_tmp[EB*32*8];    // 8 KB per-path tmp, [e][u][8]
    __shared__ float2 s_wwb[1024];       // 8 KB per-path (wb, ww) interleaved [u*32+w]
    __shared__ float  s_zp[EB*49];       // per-path z, [e][i*d3+k]
    __shared__ float  s_Y[EB*16];
    __shared__ float  s_len[EB];
    __shared__ int    s_src[EB];
    __shared__ int    s_dst[EB];

    const int t  = threadIdx.x;
    const int e0 = blockIdx.x * EB;
    const int te = t >> 5, tw = t & 31;  // fixed (edge, w/u) identity

    if (t < EB) {
        const int e = e0 + t;
        s_src[t] = eidx[e];
        s_dst[t] = eidx[N_EDGES + e];
        const float x = ev[e*3+0], y = ev[e*3+1], z = ev[e*3+2];
        const float len = sqrtf(x*x + y*y + z*z);
        const float lc = fmaxf(len, 1e-8f);
        s_len[t] = lc;
        float Yl[16];
        sh_f32(x/lc, y/lc, z/lc, Yl);
#pragma unroll
        for (int i = 0; i < 16; ++i) s_Y[t*16+i] = Yl[i];
    }
    __syncthreads();

    // gather node features, float4-coalesced
    for (int i = t; i < EB*(FEAT/4); i += 256) {
        const int e = i >> 7, c = i & 127;
        ((float4*)s_x)[i] = ((const float4*)(nf + (size_t)s_src[e]*FEAT))[c];
    }
    const float lenv = s_len[te];

    // per-thread message accumulators: l3=0 -> msg[0]; 1 -> msg[1..3]; 2 -> msg[4..8]; 3 -> msg[9..15]
    float msg[16];
#pragma unroll
    for (int i = 0; i < 16; ++i) msg[i] = 0.f;

    for (int p = 0; p < N_PATHS; ++p) {
        const int l1 = P_L1[p], l2 = P_L2[p], l3 = P_L3[p];
        const int d1 = 2*l1+1, d2 = 2*l2+1, d3 = 2*l3+1;
        const int zc = d1*d3;

        __syncthreads();  // protect s_wwb/s_tmp/s_zp overwrite vs prev-path readers
        // stage weights interleaved: s_wwb[u*32+w] = (wb, ww)
#pragma unroll
        for (int r = 0; r < 4; ++r) {
            const int i = t + 256*r;
            s_wwb[i] = make_float2(wb[p*1024 + i], ww[p*1024 + i]);
        }
        // z[e][i][k] = sum_j Y[e][l2^2+j] * C[i][j][k]  (C read from global, L1-resident)
        const float* Cg = w3j + C_OFF[p];
        for (int idx = t; idx < EB*zc; idx += 256) {
            const int e = idx / zc, r = idx - e*zc;
            const int i = r / d3, k = r - (r/d3)*d3;
            const float* Cp = Cg + i*d2*d3 + k;
            const float* Yp = s_Y + e*16 + l2*l2;
            float acc = 0.f;
            for (int j = 0; j < d2; ++j) acc = fmaf(Yp[j], Cp[j*d3], acc);
            s_zp[e*49 + r] = acc;
        }
        __syncthreads();

        // tmp[e][u][k] = sum_i x[e][32*l1^2 + u*d1 + i] * z[e][i][k]
        {
            const float* xr = s_x + te*FEAT + HIDDEN*l1*l1 + tw*d1;
            const float* zr = s_zp + te*49;
            float* tr = s_tmp + (te*32 + tw)*8;
            for (int k = 0; k < d3; ++k) {
                float acc = 0.f;
                for (int i = 0; i < d1; ++i) acc = fmaf(xr[i], zr[i*d3 + k], acc);
                tr[k] = acc;
            }
        }
        __syncthreads();

        switch (l3) {
            case 0: gemm_path<1>(te, tw, s_tmp, s_wwb, lenv, msg);     break;
            case 1: gemm_path<3>(te, tw, s_tmp, s_wwb, lenv, msg+1);   break;
            case 2: gemm_path<5>(te, tw, s_tmp, s_wwb, lenv, msg+4);   break;
            default: gemm_path<7>(te, tw, s_tmp, s_wwb, lenv, msg+9);  break;
        }
    }

    // scatter: per-thread global atomics (msg in registers; no barrier needed)
    float* ob = out + (size_t)s_dst[te]*FEAT;
    atomicAdd(&ob[tw], msg[0]);
#pragma unroll
    for (int k = 0; k < 3; ++k) atomicAdd(&ob[32  + tw*3 + k], msg[1+k]);
#pragma unroll
    for (int k = 0; k < 5; ++k) atomicAdd(&ob[128 + tw*5 + k], msg[4+k]);
#pragma unroll
    for (int k = 0; k < 7; ++k) atomicAdd(&ob[288 + tw*7 + k], msg[9+k]);
}

extern "C" void kernel_launch(void* const* d_in, const int* in_sizes, int n_in,
                              void* d_out, int out_size, void* d_ws, size_t ws_size,
                              hipStream_t stream) {
    const float* nf   = (const float*)d_in[0];
    const int*   eidx = (const int*)  d_in[1];
    const float* ev   = (const float*)d_in[2];
    const float* ww   = (const float*)d_in[3];
    const float* wb   = (const float*)d_in[4];
    float* out  = (float*)d_out;
    float* w3j  = (float*)d_ws;

    hipMemsetAsync(d_out, 0, (size_t)out_size * sizeof(float), stream);
    w3j_setup_kernel<<<N_PATHS, 256, 0, stream>>>(w3j);
    edge_kernel<<<N_EDGES/EB, 256, 0, stream>>>(nf, eidx, ev, ww, wb, w3j, out);
}

// Round 5
// 168.334 us; speedup vs baseline: 1.7509x; 1.7509x over previous
//
#include <hip/hip_runtime.h>
#include <math.h>

#define N_PATHS 23
#define HIDDEN  32
#define N_NODES 4096
#define N_EDGES 8192
#define FEAT    512
#define EB      16    // edges per block

typedef __attribute__((ext_vector_type(8))) short bf16x8;
typedef __attribute__((ext_vector_type(4))) float f32x4;

// ---- path metadata (PATHS enumeration order: l1 outer, l2, l3) ----
__device__ const int P_L1[N_PATHS] = {0,0,0,0, 1,1,1,1,1,1, 2,2,2,2,2,2,2, 3,3,3,3,3,3};
__device__ const int P_L2[N_PATHS] = {0,1,2,3, 0,1,1,2,2,3, 0,1,1,2,2,3,3, 0,1,2,2,3,3};
__device__ const int P_L3[N_PATHS] = {0,1,2,3, 1,0,2,1,3,2, 2,1,3,0,2,1,3, 3,2,1,3,0,2};
__device__ const int C_OFF[N_PATHS] = {0,1,10,35,84,93,102,147,192,297,402,427,472,577,602,727,832,1077,1126,1231,1336,1581,1630};
__device__ const int CNT_L3[4] = {4,6,7,6};
// paths grouped by l3
__device__ const int L3PATHS[N_PATHS] = {0,5,13,21, 1,4,7,11,15,19, 2,6,9,10,14,18,22, 3,8,12,16,17,20};
__device__ const int L3START[5] = {0,4,10,17,23};
__device__ const int OFF3[4] = {0,32,128,288};

// ---- 16-point Gauss-Legendre nodes/weights ----
__device__ const double GLX[16] = {
    -0.98940093499164993, -0.94457502307323258, -0.86563120238783174, -0.75540440835500303,
    -0.61787624440264375, -0.45801677765722739, -0.28160355077925891, -0.09501250983763744,
     0.09501250983763744,  0.28160355077925891,  0.45801677765722739,  0.61787624440264375,
     0.75540440835500303,  0.86563120238783174,  0.94457502307323258,  0.98940093499164993};
__device__ const double GLW[16] = {
     0.02715245941175409,  0.06225352393864789,  0.09515851168249278,  0.12462897125553387,
     0.14959598881657673,  0.16915651939500254,  0.18260341504492359,  0.18945061045506850,
     0.18945061045506850,  0.18260341504492359,  0.16915651939500254,  0.14959598881657673,
     0.12462897125553387,  0.09515851168249278,  0.06225352393864789,  0.02715245941175409};

// cos/sin(k*pi/16), exact literals
__device__ const double COSP[32] = {
  1.0,                    0.980785280403230449,  0.923879532511286756,  0.831469612302545237,
  0.707106781186547524,   0.555570233019602225,  0.382683432365089772,  0.195090322016128268,
  0.0,                   -0.195090322016128268, -0.382683432365089772, -0.555570233019602225,
 -0.707106781186547524,  -0.831469612302545237, -0.923879532511286756, -0.980785280403230449,
 -1.0,                   -0.980785280403230449, -0.923879532511286756, -0.831469612302545237,
 -0.707106781186547524,  -0.555570233019602225, -0.382683432365089772, -0.195090322016128268,
  0.0,                    0.195090322016128268,  0.382683432365089772,  0.555570233019602225,
  0.707106781186547524,   0.831469612302545237,  0.923879532511286756,  0.980785280403230449};
__device__ const double SINP[32] = {
  0.0,                    0.195090322016128268,  0.382683432365089772,  0.555570233019602225,
  0.707106781186547524,   0.831469612302545237,  0.923879532511286756,  0.980785280403230449,
  1.0,                    0.980785280403230449,  0.923879532511286756,  0.831469612302545237,
  0.707106781186547524,   0.555570233019602225,  0.382683432365089772,  0.195090322016128268,
  0.0,                   -0.195090322016128268, -0.382683432365089772, -0.555570233019602225,
 -0.707106781186547524,  -0.831469612302545237, -0.923879532511286756, -0.980785280403230449,
 -1.0,                   -0.980785280403230449, -0.923879532511286756, -0.831469612302545237,
 -0.707106781186547524,  -0.555570233019602225, -0.382683432365089772, -0.195090322016128268};

__device__ inline void sh_f64(double x, double y, double z, double* Y) {
    const double s3 = 1.7320508075688772935, s5 = 2.2360679774997896964,
                 s7 = 2.6457513110645905905, s15 = 3.8729833462074168852;
    const double c58 = 0.79056941504209483300, c38 = 0.61237243569579452455;
    Y[0] = 1.0;
    Y[1] = s3*x;  Y[2] = s3*y;  Y[3] = s3*z;
    Y[4] = s5*s3*x*z;  Y[5] = s5*s3*x*y;
    Y[6] = s5*(y*y - 0.5*(x*x + z*z));
    Y[7] = s5*s3*y*z;  Y[8] = s5*(s3/2.0)*(z*z - x*x);
    Y[9] = s7*c58*x*(3.0*z*z - x*x);
    Y[10]= s7*s15*x*y*z;
    Y[11]= s7*c38*x*(5.0*y*y - 1.0);
    Y[12]= s7*0.5*y*(5.0*y*y - 3.0);
    Y[13]= s7*c38*z*(5.0*y*y - 1.0);
    Y[14]= s7*(s15/2.0)*y*(z*z - x*x);
    Y[15]= s7*c58*z*(z*z - 3.0*x*x);
}

__device__ inline void sh_f32(float x, float y, float z, float* Y) {
    const float s3 = 1.73205080757f, s5 = 2.23606797750f, s7 = 2.64575131106f, s15 = 3.87298334621f;
    const float c58 = 0.79056941504f, c38 = 0.61237243570f;
    Y[0] = 1.0f;
    Y[1] = s3*x;  Y[2] = s3*y;  Y[3] = s3*z;
    Y[4] = s15*x*z;  Y[5] = s15*x*y;
    Y[6] = s5*(y*y - 0.5f*(x*x + z*z));
    Y[7] = s15*y*z;  Y[8] = s5*(s3*0.5f)*(z*z - x*x);
    Y[9] = s7*c58*x*(3.0f*z*z - x*x);
    Y[10]= s7*s15*x*y*z;
    Y[11]= s7*c38*x*(5.0f*y*y - 1.0f);
    Y[12]= s7*0.5f*y*(5.0f*y*y - 3.0f);
    Y[13]= s7*c38*z*(5.0f*y*y - 1.0f);
    Y[14]= s7*(s15*0.5f)*y*(z*z - x*x);
    Y[15]= s7*c58*z*(z*z - 3.0f*x*x);
}

__device__ inline unsigned short bf16rne(float x) {
    unsigned int u = __float_as_uint(x);
    unsigned int r = (u + 0x7FFFu + ((u >> 16) & 1u)) >> 16;
    return (unsigned short)r;
}
__device__ inline float bf16f(unsigned short h) {
    return __uint_as_float(((unsigned int)h) << 16);
}

// ---- setup: build (PATH_W * W3J / ||W3J||) tables, fp32 ----
__global__ __launch_bounds__(256) void w3j_setup_kernel(float* __restrict__ g_w3j) {
    __shared__ float s_Yq[512][16];
    __shared__ float s_wq[512];
    __shared__ float red[256];
    __shared__ float s_scale;

    const int p = blockIdx.x;
    const int t = threadIdx.x;
    const int l1 = P_L1[p], l2 = P_L2[p], l3 = P_L3[p];
    const int d1 = 2*l1+1, d2 = 2*l2+1, d3 = 2*l3+1;
    const int csize = d1*d2*d3;
    const double step = 2.0*3.14159265358979323846/32.0;

#pragma unroll
    for (int r = 0; r < 2; ++r) {
        const int q = t + 256*r;
        const int iu = q >> 5, ip = q & 31;
        const double u = GLX[iu];
        const double st = sqrt(fmax(1.0 - u*u, 0.0));
        double Y[16];
        sh_f64(st*COSP[ip], st*SINP[ip], u, Y);
#pragma unroll
        for (int i = 0; i < 16; ++i) s_Yq[q][i] = (float)Y[i];
        s_wq[q] = (float)(GLW[iu] * step);
    }
    __syncthreads();

    const int idx0 = t, idx1 = t + 256;
    const bool v0 = idx0 < csize, v1 = idx1 < csize;
    int a0i=0,b0i=0,c0i=0, a1i=0,b1i=0,c1i=0;
    if (v0) { int i = idx0/(d2*d3); int r = idx0 - i*(d2*d3); int j = r/d3; int k = r - j*d3;
              a0i = l1*l1+i; b0i = l2*l2+j; c0i = l3*l3+k; }
    if (v1) { int i = idx1/(d2*d3); int r = idx1 - i*(d2*d3); int j = r/d3; int k = r - j*d3;
              a1i = l1*l1+i; b1i = l2*l2+j; c1i = l3*l3+k; }

    float a0A=0.f, a0B=0.f, a1A=0.f, a1B=0.f;
#pragma unroll 4
    for (int q = 0; q < 512; q += 2) {
        const float w0 = s_wq[q], w1 = s_wq[q+1];
        if (v0) {
            a0A = fmaf(w0 * s_Yq[q][a0i]   * s_Yq[q][b0i],   s_Yq[q][c0i],   a0A);
            a0B = fmaf(w1 * s_Yq[q+1][a0i] * s_Yq[q+1][b0i], s_Yq[q+1][c0i], a0B);
        }
        if (v1) {
            a1A = fmaf(w0 * s_Yq[q][a1i]   * s_Yq[q][b1i],   s_Yq[q][c1i],   a1A);
            a1B = fmaf(w1 * s_Yq[q+1][a1i] * s_Yq[q+1][b1i], s_Yq[q+1][c1i], a1B);
        }
    }
    const float a0 = a0A + a0B, a1 = a1A + a1B;

    red[t] = a0*a0 + a1*a1;
    __syncthreads();
    for (int s = 128; s > 0; s >>= 1) {
        if (t < s) red[t] += red[t+s];
        __syncthreads();
    }
    if (t == 0) {
        const float nrm = sqrtf(red[0]);
        const float pw  = sqrtf((float)(2*l3+1) / ((float)CNT_L3[l3] * (float)HIDDEN));
        s_scale = pw / nrm;
    }
    __syncthreads();
    if (v0) g_w3j[C_OFF[p] + idx0] = a0 * s_scale;
    if (v1) g_w3j[C_OFF[p] + idx1] = a1 * s_scale;
}

// ---- prep: transpose weights to A-operand layout [p][w][u], bf16 hi/lo split ----
__global__ __launch_bounds__(256) void wprep_kernel(
    const float* __restrict__ ww, const float* __restrict__ wb,
    unsigned short* __restrict__ Awhi, unsigned short* __restrict__ Awlo,
    unsigned short* __restrict__ Abhi, unsigned short* __restrict__ Ablo) {
    const int p = blockIdx.x;
    for (int idx = threadIdx.x; idx < 1024; idx += 256) {
        const int w = idx >> 5, u = idx & 31;
        const float vw = ww[p*1024 + u*32 + w];
        const float vb = wb[p*1024 + u*32 + w];
        const unsigned short hw = bf16rne(vw);
        const unsigned short hb = bf16rne(vb);
        const int o = p*1024 + w*32 + u;
        Awhi[o] = hw;  Awlo[o] = bf16rne(vw - bf16f(hw));
        Abhi[o] = hb;  Ablo[o] = bf16rne(vb - bf16f(hb));
    }
}

// ---- tmp compute + B-operand staging (templated on d1 so xv stays in regs) ----
template<int D1>
__device__ inline void tmp_stage(int t, int d3, int xoff,
                                 const float* __restrict__ nf,
                                 const int* __restrict__ s_src,
                                 const float* __restrict__ s_zp,
                                 unsigned short* __restrict__ s_Bhi,
                                 unsigned short* __restrict__ s_Blo) {
    const int e = t >> 4, u0 = t & 15;   // thread owns u = 2u0, 2u0+1
    const float* xg = nf + (size_t)s_src[e]*FEAT + xoff + 2*u0*D1;
    float xv[2*D1];
#pragma unroll
    for (int i = 0; i < 2*D1; ++i) xv[i] = xg[i];
    const float* zr = s_zp + e*49;
    const int wv = e >> 2, el = e & 3;
    unsigned short* bh = s_Bhi + wv*1280;
    unsigned short* bl = s_Blo + wv*1280;
    for (int k = 0; k < d3; ++k) {
        float t0 = 0.f, t1 = 0.f;
#pragma unroll
        for (int i = 0; i < D1; ++i) {
            const float zz = zr[i*d3 + k];
            t0 = fmaf(xv[i],    zz, t0);
            t1 = fmaf(xv[D1+i], zz, t1);
        }
        const int c = el*d3 + k;
        const unsigned short h0 = bf16rne(t0);
        const unsigned short h1 = bf16rne(t1);
        const unsigned short g0 = bf16rne(t0 - bf16f(h0));
        const unsigned short g1 = bf16rne(t1 - bf16f(h1));
        *(unsigned int*)(bh + c*40 + 2*u0) = (unsigned int)h0 | ((unsigned int)h1 << 16);
        *(unsigned int*)(bl + c*40 + 2*u0) = (unsigned int)g0 | ((unsigned int)g1 << 16);
    }
}

// ---- main: 16 edges/block; per-l3-group MFMA GEMM ----
__global__ __launch_bounds__(256) void edge_kernel(
    const float* __restrict__ nf,   // (N_NODES, FEAT)
    const int*   __restrict__ eidx, // (2, N_EDGES)
    const float* __restrict__ ev,   // (N_EDGES, 3)
    const float* __restrict__ w3j,  // (1875,)
    const unsigned short* __restrict__ Awhi,
    const unsigned short* __restrict__ Awlo,
    const unsigned short* __restrict__ Abhi,
    const unsigned short* __restrict__ Ablo,
    float*       __restrict__ out)  // (N_NODES, FEAT) pre-zeroed
{
    __shared__ float s_C[1875];                    // W3J tables
    __shared__ float s_zp[EB*49];                  // per-path z
    __shared__ float s_Y[EB*16];
    __shared__ float s_len[EB];
    __shared__ int   s_src[EB];
    __shared__ int   s_dst[EB];
    __shared__ __align__(16) unsigned short s_Bhi[4*1280];  // [wave][col(32)][u(32)+pad8]
    __shared__ __align__(16) unsigned short s_Blo[4*1280];
    __shared__ float s_msg[EB*FEAT];               // 32 KB

    const int t    = threadIdx.x;
    const int e0   = blockIdx.x * EB;
    const int wave = t >> 6;
    const int lane = t & 63;
    const int ln   = lane & 15;    // n / m-low
    const int lq   = lane >> 4;    // quad

    if (t < EB) {
        const int e = e0 + t;
        s_src[t] = eidx[e];
        s_dst[t] = eidx[N_EDGES + e];
        const float x = ev[e*3+0], y = ev[e*3+1], z = ev[e*3+2];
        const float len = sqrtf(x*x + y*y + z*z);
        const float lc = fmaxf(len, 1e-8f);
        s_len[t] = lc;
        float Yl[16];
        sh_f32(x/lc, y/lc, z/lc, Yl);
#pragma unroll
        for (int i = 0; i < 16; ++i) s_Y[t*16+i] = Yl[i];
    }
    for (int i = t; i < 1875; i += 256) s_C[i] = w3j[i];

    for (int g = 0; g < 4; ++g) {
        const int d3g = 2*g + 1;
        const int ntg = (4*d3g + 15) >> 4;   // 1,1,2,2 column tiles per wave
        f32x4 Cw[2][2], Cb[2][2];
#pragma unroll
        for (int mt = 0; mt < 2; ++mt)
#pragma unroll
            for (int nt = 0; nt < 2; ++nt) {
                Cw[mt][nt] = (f32x4){0.f,0.f,0.f,0.f};
                Cb[mt][nt] = (f32x4){0.f,0.f,0.f,0.f};
            }

        for (int pi = L3START[g]; pi < L3START[g+1]; ++pi) {
            const int p  = L3PATHS[pi];
            const int l1 = P_L1[p], l2 = P_L2[p];
            const int d1 = 2*l1+1, d2 = 2*l2+1;
            const int zc = d1*d3g;

            __syncthreads();  // prev path's s_zp/s_B readers done (also covers prologue)

            // z[e][i][k] = sum_j Y[e][l2^2+j] * C[i][j][k]
            const float* Cp0 = s_C + C_OFF[p];
            for (int idx = t; idx < EB*zc; idx += 256) {
                const int e = idx / zc, r = idx - e*zc;
                const int i = r / d3g, k = r - i*d3g;
                const float* Cp = Cp0 + i*d2*d3g + k;
                const float* Yp = s_Y + e*16 + l2*l2;
                float acc = 0.f;
                for (int j = 0; j < d2; ++j) acc = fmaf(Yp[j], Cp[j*d3g], acc);
                s_zp[e*49 + r] = acc;
            }
            __syncthreads();

            // tmp + stage B-fragments (bf16 hi/lo) into LDS
            const int xoff = HIDDEN*l1*l1;
            switch (l1) {
                case 0: tmp_stage<1>(t, d3g, xoff, nf, s_src, s_zp, s_Bhi, s_Blo); break;
                case 1: tmp_stage<3>(t, d3g, xoff, nf, s_src, s_zp, s_Bhi, s_Blo); break;
                case 2: tmp_stage<5>(t, d3g, xoff, nf, s_src, s_zp, s_Bhi, s_Blo); break;
                default: tmp_stage<7>(t, d3g, xoff, nf, s_src, s_zp, s_Bhi, s_Blo); break;
            }
            __syncthreads();

            // GEMM: D[w][c] += W^T[w][u] * tmp[u][c], K=32, 3-pass hi/lo split
            bf16x8 awh[2], awl[2], abh[2], abl[2];
#pragma unroll
            for (int mt = 0; mt < 2; ++mt) {
                const int m = mt*16 + ln;
                const int ao = p*1024 + m*32 + lq*8;
                awh[mt] = *(const bf16x8*)(Awhi + ao);
                awl[mt] = *(const bf16x8*)(Awlo + ao);
                abh[mt] = *(const bf16x8*)(Abhi + ao);
                abl[mt] = *(const bf16x8*)(Ablo + ao);
            }
#pragma unroll
            for (int nt = 0; nt < 2; ++nt) {
                if (nt < ntg) {
                    const int bo = wave*1280 + (nt*16 + ln)*40 + lq*8;
                    const bf16x8 bh = *(const bf16x8*)(s_Bhi + bo);
                    const bf16x8 bl = *(const bf16x8*)(s_Blo + bo);
#pragma unroll
                    for (int mt = 0; mt < 2; ++mt) {
                        Cw[mt][nt] = __builtin_amdgcn_mfma_f32_16x16x32_bf16(awh[mt], bh, Cw[mt][nt], 0, 0, 0);
                        Cw[mt][nt] = __builtin_amdgcn_mfma_f32_16x16x32_bf16(awh[mt], bl, Cw[mt][nt], 0, 0, 0);
                        Cw[mt][nt] = __builtin_amdgcn_mfma_f32_16x16x32_bf16(awl[mt], bh, Cw[mt][nt], 0, 0, 0);
                        Cb[mt][nt] = __builtin_amdgcn_mfma_f32_16x16x32_bf16(abh[mt], bh, Cb[mt][nt], 0, 0, 0);
                        Cb[mt][nt] = __builtin_amdgcn_mfma_f32_16x16x32_bf16(abh[mt], bl, Cb[mt][nt], 0, 0, 0);
                        Cb[mt][nt] = __builtin_amdgcn_mfma_f32_16x16x32_bf16(abl[mt], bh, Cb[mt][nt], 0, 0, 0);
                    }
                }
            }
        }

        // group epilogue: msg = len*Cw + Cb  (wave-private region, unique owners)
#pragma unroll
        for (int nt = 0; nt < 2; ++nt) {
            if (nt < ntg) {
                const int c = nt*16 + ln;
                if (c < 4*d3g) {
                    const int e = wave*4 + c/d3g;
                    const int k = c - (c/d3g)*d3g;
                    const float len = s_len[e];
                    float* mp = s_msg + e*FEAT + OFF3[g] + k;
#pragma unroll
                    for (int mt = 0; mt < 2; ++mt) {
#pragma unroll
                        for (int r = 0; r < 4; ++r) {
                            const int w = mt*16 + lq*4 + r;
                            mp[w*d3g] = fmaf(len, Cw[mt][nt][r], Cb[mt][nt][r]);
                        }
                    }
                }
            }
        }
    }
    __syncthreads();

    // coalesced scatter
    for (int i = t; i < EB*FEAT; i += 256) {
        const int e = i >> 9, m = i & 511;
        atomicAdd(&out[(size_t)s_dst[e]*FEAT + m], s_msg[i]);
    }
}

extern "C" void kernel_launch(void* const* d_in, const int* in_sizes, int n_in,
                              void* d_out, int out_size, void* d_ws, size_t ws_size,
                              hipStream_t stream) {
    const float* nf   = (const float*)d_in[0];
    const int*   eidx = (const int*)  d_in[1];
    const float* ev   = (const float*)d_in[2];
    const float* ww   = (const float*)d_in[3];
    const float* wb   = (const float*)d_in[4];
    float* out = (float*)d_out;

    float* w3j = (float*)d_ws;                                   // 7500 B
    unsigned short* Awhi = (unsigned short*)((char*)d_ws + 16384);
    unsigned short* Awlo = Awhi + N_PATHS*1024;
    unsigned short* Abhi = Awlo + N_PATHS*1024;
    unsigned short* Ablo = Abhi + N_PATHS*1024;                  // ends at 204800 B

    hipMemsetAsync(d_out, 0, (size_t)out_size * sizeof(float), stream);
    w3j_setup_kernel<<<N_PATHS, 256, 0, stream>>>(w3j);
    wprep_kernel<<<N_PATHS, 256, 0, stream>>>(ww, wb, Awhi, Awlo, Abhi, Ablo);
    edge_kernel<<<N_EDGES/EB, 256, 0, stream>>>(nf, eidx, ev, w3j, Awhi, Awlo, Abhi, Ablo, out);
}

// Round 6
// 154.593 us; speedup vs baseline: 1.9066x; 1.0889x over previous
//
#include <hip/hip_runtime.h>
#include <math.h>

#define N_PATHS 23
#define HIDDEN  32
#define N_NODES 4096
#define N_EDGES 8192
#define FEAT    512
#define EB      8     // edges per block
#define BLK     128   // threads per block (2 waves)

typedef __attribute__((ext_vector_type(8))) short bf16x8;
typedef __attribute__((ext_vector_type(4))) float f32x4;

// ---- path metadata (PATHS enumeration order: l1 outer, l2, l3) ----
__device__ const int P_L1[N_PATHS] = {0,0,0,0, 1,1,1,1,1,1, 2,2,2,2,2,2,2, 3,3,3,3,3,3};
__device__ const int P_L2[N_PATHS] = {0,1,2,3, 0,1,1,2,2,3, 0,1,1,2,2,3,3, 0,1,2,2,3,3};
__device__ const int P_L3[N_PATHS] = {0,1,2,3, 1,0,2,1,3,2, 2,1,3,0,2,1,3, 3,2,1,3,0,2};
__device__ const int C_OFF[N_PATHS] = {0,1,10,35,84,93,102,147,192,297,402,427,472,577,602,727,832,1077,1126,1231,1336,1581,1630};
__device__ const int CNT_L3[4] = {4,6,7,6};
// paths grouped by l3
__device__ const int L3PATHS[N_PATHS] = {0,5,13,21, 1,4,7,11,15,19, 2,6,9,10,14,18,22, 3,8,12,16,17,20};
__device__ const int L3START[5] = {0,4,10,17,23};
__device__ const int OFF3[4] = {0,32,128,288};

// ---- 16-point Gauss-Legendre nodes/weights ----
__device__ const double GLX[16] = {
    -0.98940093499164993, -0.94457502307323258, -0.86563120238783174, -0.75540440835500303,
    -0.61787624440264375, -0.45801677765722739, -0.28160355077925891, -0.09501250983763744,
     0.09501250983763744,  0.28160355077925891,  0.45801677765722739,  0.61787624440264375,
     0.75540440835500303,  0.86563120238783174,  0.94457502307323258,  0.98940093499164993};
__device__ const double GLW[16] = {
     0.02715245941175409,  0.06225352393864789,  0.09515851168249278,  0.12462897125553387,
     0.14959598881657673,  0.16915651939500254,  0.18260341504492359,  0.18945061045506850,
     0.18945061045506850,  0.18260341504492359,  0.16915651939500254,  0.14959598881657673,
     0.12462897125553387,  0.09515851168249278,  0.06225352393864789,  0.02715245941175409};

// cos/sin(k*pi/16), exact literals
__device__ const double COSP[32] = {
  1.0,                    0.980785280403230449,  0.923879532511286756,  0.831469612302545237,
  0.707106781186547524,   0.555570233019602225,  0.382683432365089772,  0.195090322016128268,
  0.0,                   -0.195090322016128268, -0.382683432365089772, -0.555570233019602225,
 -0.707106781186547524,  -0.831469612302545237, -0.923879532511286756, -0.980785280403230449,
 -1.0,                   -0.980785280403230449, -0.923879532511286756, -0.831469612302545237,
 -0.707106781186547524,  -0.555570233019602225, -0.382683432365089772, -0.195090322016128268,
  0.0,                    0.195090322016128268,  0.382683432365089772,  0.555570233019602225,
  0.707106781186547524,   0.831469612302545237,  0.923879532511286756,  0.980785280403230449};
__device__ const double SINP[32] = {
  0.0,                    0.195090322016128268,  0.382683432365089772,  0.555570233019602225,
  0.707106781186547524,   0.831469612302545237,  0.923879532511286756,  0.980785280403230449,
  1.0,                    0.980785280403230449,  0.923879532511286756,  0.831469612302545237,
  0.707106781186547524,   0.555570233019602225,  0.382683432365089772,  0.195090322016128268,
  0.0,                   -0.195090322016128268, -0.382683432365089772, -0.555570233019602225,
 -0.707106781186547524,  -0.831469612302545237, -0.923879532511286756, -0.980785280403230449,
 -1.0,                   -0.980785280403230449, -0.923879532511286756, -0.831469612302545237,
 -0.707106781186547524,  -0.555570233019602225, -0.382683432365089772, -0.195090322016128268};

__device__ inline void sh_f64(double x, double y, double z, double* Y) {
    const double s3 = 1.7320508075688772935, s5 = 2.2360679774997896964,
                 s7 = 2.6457513110645905905, s15 = 3.8729833462074168852;
    const double c58 = 0.79056941504209483300, c38 = 0.61237243569579452455;
    Y[0] = 1.0;
    Y[1] = s3*x;  Y[2] = s3*y;  Y[3] = s3*z;
    Y[4] = s5*s3*x*z;  Y[5] = s5*s3*x*y;
    Y[6] = s5*(y*y - 0.5*(x*x + z*z));
    Y[7] = s5*s3*y*z;  Y[8] = s5*(s3/2.0)*(z*z - x*x);
    Y[9] = s7*c58*x*(3.0*z*z - x*x);
    Y[10]= s7*s15*x*y*z;
    Y[11]= s7*c38*x*(5.0*y*y - 1.0);
    Y[12]= s7*0.5*y*(5.0*y*y - 3.0);
    Y[13]= s7*c38*z*(5.0*y*y - 1.0);
    Y[14]= s7*(s15/2.0)*y*(z*z - x*x);
    Y[15]= s7*c58*z*(z*z - 3.0*x*x);
}

__device__ inline void sh_f32(float x, float y, float z, float* Y) {
    const float s3 = 1.73205080757f, s5 = 2.23606797750f, s7 = 2.64575131106f, s15 = 3.87298334621f;
    const float c58 = 0.79056941504f, c38 = 0.61237243570f;
    Y[0] = 1.0f;
    Y[1] = s3*x;  Y[2] = s3*y;  Y[3] = s3*z;
    Y[4] = s15*x*z;  Y[5] = s15*x*y;
    Y[6] = s5*(y*y - 0.5f*(x*x + z*z));
    Y[7] = s15*y*z;  Y[8] = s5*(s3*0.5f)*(z*z - x*x);
    Y[9] = s7*c58*x*(3.0f*z*z - x*x);
    Y[10]= s7*s15*x*y*z;
    Y[11]= s7*c38*x*(5.0f*y*y - 1.0f);
    Y[12]= s7*0.5f*y*(5.0f*y*y - 3.0f);
    Y[13]= s7*c38*z*(5.0f*y*y - 1.0f);
    Y[14]= s7*(s15*0.5f)*y*(z*z - x*x);
    Y[15]= s7*c58*z*(z*z - 3.0f*x*x);
}

__device__ inline unsigned short bf16rne(float x) {
    unsigned int u = __float_as_uint(x);
    unsigned int r = (u + 0x7FFFu + ((u >> 16) & 1u)) >> 16;
    return (unsigned short)r;
}
__device__ inline float bf16f(unsigned short h) {
    return __uint_as_float(((unsigned int)h) << 16);
}

// ---- setup: (entry x quad-chunk)-parallel quadrature; 512 thr/block ----
__global__ __launch_bounds__(512) void w3j_setup_kernel(float* __restrict__ g_w3j) {
    __shared__ float s_Yq[512][17];   // pad 17: bank spread for q-stride-4 reads
    __shared__ float s_wq[512];
    __shared__ float s_part[256];
    __shared__ float red[256];
    __shared__ float s_scale;

    const int p = blockIdx.x;
    const int t = threadIdx.x;
    const int l1 = P_L1[p], l2 = P_L2[p], l3 = P_L3[p];
    const int d2 = 2*l2+1, d3 = 2*l3+1;
    const int csize = (2*l1+1)*d2*d3;
    const double step = 2.0*3.14159265358979323846/32.0;

    // phase A: one quadrature point per thread
    {
        const int q = t, iu = q >> 5, ip = q & 31;
        const double u = GLX[iu];
        const double st = sqrt(fmax(1.0 - u*u, 0.0));
        double Y[16];
        sh_f64(st*COSP[ip], st*SINP[ip], u, Y);
#pragma unroll
        for (int i = 0; i < 16; ++i) s_Yq[q][i] = (float)Y[i];
        s_wq[q] = (float)(GLW[iu] * step);
    }
    __syncthreads();

    // phase B: 4 threads per entry, 128 interleaved points each, shuffle-reduce
    const int entry0 = t >> 2, sub = t & 3;
#pragma unroll
    for (int pass = 0; pass < 2; ++pass) {
        const int entry = entry0 + pass*128;
        float acc = 0.f;
        if (entry < csize) {
            const int i = entry/(d2*d3); const int r = entry - i*(d2*d3);
            const int j = r/d3; const int k = r - j*d3;
            const int ai = l1*l1+i, bi = l2*l2+j, ci = l3*l3+k;
#pragma unroll 4
            for (int it = 0; it < 128; ++it) {
                const int q = it*4 + sub;
                acc = fmaf(s_wq[q] * s_Yq[q][ai] * s_Yq[q][bi], s_Yq[q][ci], acc);
            }
        }
        acc += __shfl_xor(acc, 1);
        acc += __shfl_xor(acc, 2);
        if (sub == 0 && entry < csize) s_part[entry] = acc;
    }
    __syncthreads();

    if (t < 256) { const float v = (t < csize) ? s_part[t] : 0.f; red[t] = v*v; }
    __syncthreads();
    for (int s = 128; s > 0; s >>= 1) {
        if (t < s) red[t] += red[t+s];
        __syncthreads();
    }
    if (t == 0) {
        const float pw = sqrtf((float)(2*l3+1) / ((float)CNT_L3[l3] * (float)HIDDEN));
        s_scale = pw / sqrtf(red[0]);
    }
    __syncthreads();
    if (t < csize) g_w3j[C_OFF[p] + t] = s_part[t] * s_scale;
}

// ---- prep: transpose weights to A-operand layout [p][w][u], bf16 hi/lo split ----
__global__ __launch_bounds__(256) void wprep_kernel(
    const float* __restrict__ ww, const float* __restrict__ wb,
    unsigned short* __restrict__ Awhi, unsigned short* __restrict__ Awlo,
    unsigned short* __restrict__ Abhi, unsigned short* __restrict__ Ablo) {
    const int p = blockIdx.x;
    for (int idx = threadIdx.x; idx < 1024; idx += 256) {
        const int w = idx >> 5, u = idx & 31;
        const float vw = ww[p*1024 + u*32 + w];
        const float vb = wb[p*1024 + u*32 + w];
        const unsigned short hw = bf16rne(vw);
        const unsigned short hb = bf16rne(vb);
        const int o = p*1024 + w*32 + u;
        Awhi[o] = hw;  Awlo[o] = bf16rne(vw - bf16f(hw));
        Abhi[o] = hb;  Ablo[o] = bf16rne(vb - bf16f(hb));
    }
}

// ---- tmp compute + B-operand staging (templated on d1 so xv stays in regs) ----
template<int D1>
__device__ inline void tmp_stage(int t, int d3, int xoff,
                                 const float* __restrict__ nf,
                                 const int* __restrict__ s_src,
                                 const float* __restrict__ s_zp,
                                 unsigned short* __restrict__ s_Bhi,
                                 unsigned short* __restrict__ s_Blo) {
    const int e = t >> 4, u0 = t & 15;   // thread owns u = 2u0, 2u0+1
    const float* xg = nf + (size_t)s_src[e]*FEAT + xoff + 2*u0*D1;
    float xv[2*D1];
#pragma unroll
    for (int i = 0; i < 2*D1; ++i) xv[i] = xg[i];
    const float* zr = s_zp + e*49;
    const int wv = e >> 2, el = e & 3;
    unsigned short* bh = s_Bhi + wv*1280;
    unsigned short* bl = s_Blo + wv*1280;
    for (int k = 0; k < d3; ++k) {
        float t0 = 0.f, t1 = 0.f;
#pragma unroll
        for (int i = 0; i < D1; ++i) {
            const float zz = zr[i*d3 + k];
            t0 = fmaf(xv[i],    zz, t0);
            t1 = fmaf(xv[D1+i], zz, t1);
        }
        const int c = el*d3 + k;
        const unsigned short h0 = bf16rne(t0);
        const unsigned short h1 = bf16rne(t1);
        const unsigned short g0 = bf16rne(t0 - bf16f(h0));
        const unsigned short g1 = bf16rne(t1 - bf16f(h1));
        *(unsigned int*)(bh + c*40 + 2*u0) = (unsigned int)h0 | ((unsigned int)h1 << 16);
        *(unsigned int*)(bl + c*40 + 2*u0) = (unsigned int)g0 | ((unsigned int)g1 << 16);
    }
}

// ---- main: 8 edges/block, 128 threads (2 waves); per-l3-group MFMA GEMM ----
__global__ __launch_bounds__(BLK) void edge_kernel(
    const float* __restrict__ nf,   // (N_NODES, FEAT)
    const int*   __restrict__ eidx, // (2, N_EDGES)
    const float* __restrict__ ev,   // (N_EDGES, 3)
    const float* __restrict__ w3j,  // (1875,)
    const unsigned short* __restrict__ Awhi,
    const unsigned short* __restrict__ Awlo,
    const unsigned short* __restrict__ Abhi,
    const unsigned short* __restrict__ Ablo,
    float*       __restrict__ out)  // (N_NODES, FEAT) pre-zeroed
{
    __shared__ float s_C[1875];                    // 7.5 KB W3J tables
    __shared__ float s_zp[EB*49];                  // per-path z
    __shared__ float s_Y[EB*16];
    __shared__ float s_len[EB];
    __shared__ int   s_src[EB];
    __shared__ int   s_dst[EB];
    __shared__ __align__(16) unsigned short s_Bhi[2*1280];  // [wave][col(32)][u(32)+pad8]
    __shared__ __align__(16) unsigned short s_Blo[2*1280];
    __shared__ float s_msg[EB*FEAT];               // 16 KB

    const int t    = threadIdx.x;
    const int e0   = blockIdx.x * EB;
    const int wave = t >> 6;
    const int lane = t & 63;
    const int ln   = lane & 15;    // n / m-low
    const int lq   = lane >> 4;    // quad

    if (t < EB) {
        const int e = e0 + t;
        s_src[t] = eidx[e];
        s_dst[t] = eidx[N_EDGES + e];
        const float x = ev[e*3+0], y = ev[e*3+1], z = ev[e*3+2];
        const float len = sqrtf(x*x + y*y + z*z);
        const float lc = fmaxf(len, 1e-8f);
        s_len[t] = lc;
        float Yl[16];
        sh_f32(x/lc, y/lc, z/lc, Yl);
#pragma unroll
        for (int i = 0; i < 16; ++i) s_Y[t*16+i] = Yl[i];
    }
    for (int i = t; i < 1875; i += BLK) s_C[i] = w3j[i];

    for (int g = 0; g < 4; ++g) {
        const int d3g = 2*g + 1;
        const int ntg = (4*d3g + 15) >> 4;   // 1,1,2,2 column tiles per wave
        f32x4 Cw[2][2], Cb[2][2];
#pragma unroll
        for (int mt = 0; mt < 2; ++mt)
#pragma unroll
            for (int nt = 0; nt < 2; ++nt) {
                Cw[mt][nt] = (f32x4){0.f,0.f,0.f,0.f};
                Cb[mt][nt] = (f32x4){0.f,0.f,0.f,0.f};
            }

        for (int pi = L3START[g]; pi < L3START[g+1]; ++pi) {
            const int p  = L3PATHS[pi];
            const int l1 = P_L1[p], l2 = P_L2[p];
            const int d1 = 2*l1+1, d2 = 2*l2+1;
            const int zc = d1*d3g;

            __syncthreads();  // prev path's s_zp/s_B readers done (also covers prologue)

            // z[e][i][k] = sum_j Y[e][l2^2+j] * C[i][j][k]
            const float* Cp0 = s_C + C_OFF[p];
            for (int idx = t; idx < EB*zc; idx += BLK) {
                const int e = idx / zc, r = idx - e*zc;
                const int i = r / d3g, k = r - i*d3g;
                const float* Cp = Cp0 + i*d2*d3g + k;
                const float* Yp = s_Y + e*16 + l2*l2;
                float acc = 0.f;
                for (int j = 0; j < d2; ++j) acc = fmaf(Yp[j], Cp[j*d3g], acc);
                s_zp[e*49 + r] = acc;
            }
            __syncthreads();

            // tmp + stage B-fragments (bf16 hi/lo) into LDS
            const int xoff = HIDDEN*l1*l1;
            switch (l1) {
                case 0: tmp_stage<1>(t, d3g, xoff, nf, s_src, s_zp, s_Bhi, s_Blo); break;
                case 1: tmp_stage<3>(t, d3g, xoff, nf, s_src, s_zp, s_Bhi, s_Blo); break;
                case 2: tmp_stage<5>(t, d3g, xoff, nf, s_src, s_zp, s_Bhi, s_Blo); break;
                default: tmp_stage<7>(t, d3g, xoff, nf, s_src, s_zp, s_Bhi, s_Blo); break;
            }
            __syncthreads();

            // GEMM: D[w][c] += W^T[w][u] * tmp[u][c], K=32, 3-pass hi/lo split
            bf16x8 awh[2], awl[2], abh[2], abl[2];
#pragma unroll
            for (int mt = 0; mt < 2; ++mt) {
                const int m = mt*16 + ln;
                const int ao = p*1024 + m*32 + lq*8;
                awh[mt] = *(const bf16x8*)(Awhi + ao);
                awl[mt] = *(const bf16x8*)(Awlo + ao);
                abh[mt] = *(const bf16x8*)(Abhi + ao);
                abl[mt] = *(const bf16x8*)(Ablo + ao);
            }
#pragma unroll
            for (int nt = 0; nt < 2; ++nt) {
                if (nt < ntg) {
                    const int bo = wave*1280 + (nt*16 + ln)*40 + lq*8;
                    const bf16x8 bh = *(const bf16x8*)(s_Bhi + bo);
                    const bf16x8 bl = *(const bf16x8*)(s_Blo + bo);
#pragma unroll
                    for (int mt = 0; mt < 2; ++mt) {
                        Cw[mt][nt] = __builtin_amdgcn_mfma_f32_16x16x32_bf16(awh[mt], bh, Cw[mt][nt], 0, 0, 0);
                        Cw[mt][nt] = __builtin_amdgcn_mfma_f32_16x16x32_bf16(awh[mt], bl, Cw[mt][nt], 0, 0, 0);
                        Cw[mt][nt] = __builtin_amdgcn_mfma_f32_16x16x32_bf16(awl[mt], bh, Cw[mt][nt], 0, 0, 0);
                        Cb[mt][nt] = __builtin_amdgcn_mfma_f32_16x16x32_bf16(abh[mt], bh, Cb[mt][nt], 0, 0, 0);
                        Cb[mt][nt] = __builtin_amdgcn_mfma_f32_16x16x32_bf16(abh[mt], bl, Cb[mt][nt], 0, 0, 0);
                        Cb[mt][nt] = __builtin_amdgcn_mfma_f32_16x16x32_bf16(abl[mt], bh, Cb[mt][nt], 0, 0, 0);
                    }
                }
            }
        }

        // group epilogue: msg = len*Cw + Cb  (wave-private region, unique owners)
#pragma unroll
        for (int nt = 0; nt < 2; ++nt) {
            if (nt < ntg) {
                const int c = nt*16 + ln;
                if (c < 4*d3g) {
                    const int e = wave*4 + c/d3g;
                    const int k = c - (c/d3g)*d3g;
                    const float len = s_len[e];
                    float* mp = s_msg + e*FEAT + OFF3[g] + k;
#pragma unroll
                    for (int mt = 0; mt < 2; ++mt) {
#pragma unroll
                        for (int r = 0; r < 4; ++r) {
                            const int w = mt*16 + lq*4 + r;
                            mp[w*d3g] = fmaf(len, Cw[mt][nt][r], Cb[mt][nt][r]);
                        }
                    }
                }
            }
        }
    }
    __syncthreads();

    // coalesced scatter
    for (int i = t; i < EB*FEAT; i += BLK) {
        const int e = i >> 9, m = i & 511;
        atomicAdd(&out[(size_t)s_dst[e]*FEAT + m], s_msg[i]);
    }
}

extern "C" void kernel_launch(void* const* d_in, const int* in_sizes, int n_in,
                              void* d_out, int out_size, void* d_ws, size_t ws_size,
                              hipStream_t stream) {
    const float* nf   = (const float*)d_in[0];
    const int*   eidx = (const int*)  d_in[1];
    const float* ev   = (const float*)d_in[2];
    const float* ww   = (const float*)d_in[3];
    const float* wb   = (const float*)d_in[4];
    float* out = (float*)d_out;

    float* w3j = (float*)d_ws;                                   // 7500 B
    unsigned short* Awhi = (unsigned short*)((char*)d_ws + 16384);
    unsigned short* Awlo = Awhi + N_PATHS*1024;
    unsigned short* Abhi = Awlo + N_PATHS*1024;
    unsigned short* Ablo = Abhi + N_PATHS*1024;                  // ends at 204800 B

    hipMemsetAsync(d_out, 0, (size_t)out_size * sizeof(float), stream);
    w3j_setup_kernel<<<N_PATHS, 512, 0, stream>>>(w3j);
    wprep_kernel<<<N_PATHS, 256, 0, stream>>>(ww, wb, Awhi, Awlo, Abhi, Ablo);
    edge_kernel<<<N_EDGES/EB, BLK, 0, stream>>>(nf, eidx, ev, w3j, Awhi, Awlo, Abhi, Ablo, out);
}